// Round 3
// baseline (418.649 us; speedup 1.0000x reference)
//
#include <hip/hip_runtime.h>
#include <cstdint>
#include <cstddef>

// Problem dims (fixed by reference): x [8,1024,1024] -> M=8192, dim=1024, hidden=4096
#define DIM   1024
#define HID   4096
#define MROWS 8192

typedef __attribute__((ext_vector_type(8))) __bf16 bf16x8;
typedef __attribute__((ext_vector_type(4))) float  f32x4;

__device__ __forceinline__ unsigned short f2bf(float f) {
  unsigned int u = __float_as_uint(f);
  u += 0x7fffu + ((u >> 16) & 1u);   // round-to-nearest-even
  return (unsigned short)(u >> 16);
}
__device__ __forceinline__ float bf2f(unsigned int lo16) {
  return __uint_as_float(lo16 << 16);
}

// tanh-form GELU: ~7 VALU instrs vs ~25 for erff; deviation from exact ~1e-3.
__device__ __forceinline__ float fast_gelu(float v) {
  float u = v * (0.79788456080286536f + 0.035677408136300125f * v * v);
  float e = __builtin_amdgcn_exp2f(u * 2.8853900817779268f);   // exp(2u)
  float r = __builtin_amdgcn_rcpf(e + 1.0f);
  return v - v * r;   // = v * e/(e+1) = 0.5 v (1+tanh(u))
}

// ---- async global->LDS, 16B per lane (m97 pattern) ----
__device__ __forceinline__ void gld16(const void* g, void* l) {
  auto* gp = reinterpret_cast<__attribute__((address_space(1))) unsigned int*>(
      reinterpret_cast<uintptr_t>(g));
  auto* lp = reinterpret_cast<__attribute__((address_space(3))) unsigned int*>(
      reinterpret_cast<uintptr_t>(l));
  __builtin_amdgcn_global_load_lds(gp, lp, 16, 0, 0);
}

// ---- block reduce (two values), 256 threads = 4 waves ----
__device__ __forceinline__ void block_reduce2(float& a, float& b, int tid) {
#pragma unroll
  for (int off = 32; off > 0; off >>= 1) {
    a += __shfl_xor(a, off, 64);
    b += __shfl_xor(b, off, 64);
  }
  __shared__ float red[8];
  if ((tid & 63) == 0) { red[tid >> 6] = a; red[4 + (tid >> 6)] = b; }
  __syncthreads();
  a = red[0] + red[1] + red[2] + red[3];
  b = red[4] + red[5] + red[6] + red[7];
}

// ---- stage 1: per-block partial sums of |w| (4096 floats per block) ----
// blocks 0..1023 -> w1, 1024..2047 -> w2 (both are 4M elements)
__global__ __launch_bounds__(256)
void absum_kernel(const float* __restrict__ w1, const float* __restrict__ w2,
                  float* __restrict__ part) {
  int tid = threadIdx.x;
  const float* w = (blockIdx.x < 1024) ? w1 : w2;
  int blk = blockIdx.x & 1023;
  const float4* base = (const float4*)w + (size_t)blk * 1024;
  float s = 0.f;
#pragma unroll
  for (int i = 0; i < 4; ++i) {
    float4 v = base[tid + i * 256];
    s += fabsf(v.x) + fabsf(v.y) + fabsf(v.z) + fabsf(v.w);
  }
#pragma unroll
  for (int off = 32; off > 0; off >>= 1) s += __shfl_xor(s, off, 64);
  __shared__ float red[4];
  if ((tid & 63) == 0) red[tid >> 6] = s;
  __syncthreads();
  if (tid == 0) part[blockIdx.x] = red[0] + red[1] + red[2] + red[3];
}

// ---- stage 2: final deterministic reduce -> clipped means for both weights ----
__global__ __launch_bounds__(256)
void final_reduce(const float* __restrict__ part, float* __restrict__ out) {
  int tid = threadIdx.x;
  float a = 0.f, b = 0.f;
  for (int i = tid; i < 1024; i += 256) { a += part[i]; b += part[1024 + i]; }
  block_reduce2(a, b, tid);
  if (tid == 0) {
    out[0] = fmaxf(a * (1.0f / 4194304.0f), 1e-5f);  // mean|w1| clipped
    out[1] = fmaxf(b * (1.0f / 4194304.0f), 1e-5f);  // mean|w2| clipped
  }
}

// ---- ternary quantize: q = clip(rint(w/mean),-1,1) stored as bf16 {-1,0,1} ----
// blocks 0..511 -> w1->q1 (scale[0]), 512..1023 -> w2->q2 (scale[1])
__global__ __launch_bounds__(256)
void quant_kernel(const float* __restrict__ w1, unsigned short* __restrict__ q1,
                  const float* __restrict__ w2, unsigned short* __restrict__ q2,
                  const float* __restrict__ meanp) {
  const int n4 = 1048576;
  const float* w;
  unsigned short* q;
  float sc;
  int bid = blockIdx.x;
  if (bid < 512) { w = w1; q = q1; sc = 1.0f / meanp[0]; }
  else           { w = w2; q = q2; sc = 1.0f / meanp[1]; bid -= 512; }
  int i = bid * 256 + threadIdx.x;
  for (; i < n4; i += 512 * 256) {
    float4 v = ((const float4*)w)[i];
    float t0 = fminf(fmaxf(rintf(v.x * sc), -1.f), 1.f);
    float t1 = fminf(fmaxf(rintf(v.y * sc), -1.f), 1.f);
    float t2 = fminf(fmaxf(rintf(v.z * sc), -1.f), 1.f);
    float t3 = fminf(fmaxf(rintf(v.w * sc), -1.f), 1.f);
    uint2 r;
    r.x = (unsigned)f2bf(t0) | ((unsigned)f2bf(t1) << 16);
    r.y = (unsigned)f2bf(t2) | ((unsigned)f2bf(t3) << 16);
    ((uint2*)q)[i] = r;
  }
}

// ---- init d_out with broadcast bias2 (split-K atomic accumulation base) ----
__global__ __launch_bounds__(256)
void init_out_kernel(float* __restrict__ out, const float* __restrict__ bias) {
  // out is [8192,1024] fp32 = 2M float4; bias row = 256 float4
  int i = blockIdx.x * 256 + threadIdx.x;           // float4 index
  float4 bv = ((const float4*)bias)[i & 255];
  ((float4*)out)[i] = bv;
}

// ---- LN1: fp32 [8192,1024] -> bf16 normalized ----
__global__ __launch_bounds__(256)
void ln1_kernel(const float* __restrict__ x, const float* __restrict__ g,
                const float* __restrict__ b, unsigned short* __restrict__ out) {
  int tid = threadIdx.x;
  const float4* xr = (const float4*)(x + (size_t)blockIdx.x * DIM);
  float4 v = xr[tid];
  float s  = v.x + v.y + v.z + v.w;
  float ss = v.x * v.x + v.y * v.y + v.z * v.z + v.w * v.w;
  block_reduce2(s, ss, tid);
  float mu  = s * (1.0f / DIM);
  float var = ss * (1.0f / DIM) - mu * mu;
  float rs  = rsqrtf(var + 1e-5f);
  float4 gg = ((const float4*)g)[tid];
  float4 bb = ((const float4*)b)[tid];
  uint2 r;
  r.x = (unsigned)f2bf((v.x - mu) * rs * gg.x + bb.x) |
        ((unsigned)f2bf((v.y - mu) * rs * gg.y + bb.y) << 16);
  r.y = (unsigned)f2bf((v.z - mu) * rs * gg.z + bb.z) |
        ((unsigned)f2bf((v.w - mu) * rs * gg.w + bb.w) << 16);
  *(uint2*)(out + (size_t)blockIdx.x * DIM + tid * 4) = r;
}

// ---- LN2: in-place on bf16 h [8192,4096] ----
__global__ __launch_bounds__(256)
void ln2_kernel(unsigned short* __restrict__ h, const float* __restrict__ g,
                const float* __restrict__ b) {
  int tid = threadIdx.x;
  unsigned short* hr = h + (size_t)blockIdx.x * HID;
  uint4 pa = ((uint4*)hr)[tid];
  uint4 pb = ((uint4*)hr)[tid + 256];
  float va[8], vb[8];
  {
    unsigned int* pu = (unsigned int*)&pa;
#pragma unroll
    for (int j = 0; j < 4; ++j) {
      va[2 * j]     = bf2f(pu[j] & 0xffffu);
      va[2 * j + 1] = __uint_as_float(pu[j] & 0xffff0000u);
    }
    pu = (unsigned int*)&pb;
#pragma unroll
    for (int j = 0; j < 4; ++j) {
      vb[2 * j]     = bf2f(pu[j] & 0xffffu);
      vb[2 * j + 1] = __uint_as_float(pu[j] & 0xffff0000u);
    }
  }
  float s = 0.f, ss = 0.f;
#pragma unroll
  for (int j = 0; j < 8; ++j) {
    s += va[j] + vb[j];
    ss += va[j] * va[j] + vb[j] * vb[j];
  }
  block_reduce2(s, ss, tid);
  float mu  = s * (1.0f / HID);
  float var = ss * (1.0f / HID) - mu * mu;
  float rs  = rsqrtf(var + 1e-5f);

  const float4* g4 = (const float4*)g;
  const float4* b4 = (const float4*)b;
  float4 ga0 = g4[tid * 2], ga1 = g4[tid * 2 + 1];
  float4 ba0 = b4[tid * 2], bb1 = b4[tid * 2 + 1];
  float4 gb0 = g4[(tid + 256) * 2], gb1 = g4[(tid + 256) * 2 + 1];
  float4 bb0 = b4[(tid + 256) * 2], bb3 = b4[(tid + 256) * 2 + 1];
  float gva[8] = {ga0.x, ga0.y, ga0.z, ga0.w, ga1.x, ga1.y, ga1.z, ga1.w};
  float bva[8] = {ba0.x, ba0.y, ba0.z, ba0.w, bb1.x, bb1.y, bb1.z, bb1.w};
  float gvb[8] = {gb0.x, gb0.y, gb0.z, gb0.w, gb1.x, gb1.y, gb1.z, gb1.w};
  float bvb[8] = {bb0.x, bb0.y, bb0.z, bb0.w, bb3.x, bb3.y, bb3.z, bb3.w};

  uint4 ra, rb;
  unsigned int* ru = (unsigned int*)&ra;
#pragma unroll
  for (int j = 0; j < 4; ++j) {
    unsigned lo = f2bf((va[2 * j] - mu) * rs * gva[2 * j] + bva[2 * j]);
    unsigned hi = f2bf((va[2 * j + 1] - mu) * rs * gva[2 * j + 1] + bva[2 * j + 1]);
    ru[j] = lo | (hi << 16);
  }
  ru = (unsigned int*)&rb;
#pragma unroll
  for (int j = 0; j < 4; ++j) {
    unsigned lo = f2bf((vb[2 * j] - mu) * rs * gvb[2 * j] + bvb[2 * j]);
    unsigned hi = f2bf((vb[2 * j + 1] - mu) * rs * gvb[2 * j + 1] + bvb[2 * j + 1]);
    ru[j] = lo | (hi << 16);
  }
  ((uint4*)hr)[tid]       = ra;
  ((uint4*)hr)[tid + 256] = rb;
}

// ---- GEMM C[m,n] = sum_k A[m,k]*B[n,k] * wscale (+bias) (+gelu) ----
// A: bf16 [M,lda] row-major; B: bf16 ternary [N,lda] row-major; Kiter <= lda.
// Split-K: blockIdx.z selects K-slice of length Kiter (base += z*Kiter).
// 128x128 tile, BK=32, 256 thr = 4 waves (2x2 of 64x64), 16x16x32 bf16 MFMA.
// LDS is XOR-granule-swizzled (conflict-free, see round-2 note).
// MODE 0: store fp32 (v*wscale + bias)       -- full-K
// MODE 1: store bf16 gelu(v*wscale + bias)   -- full-K
// MODE 2: unsafeAtomicAdd fp32 (v*wscale)    -- split-K, bias pre-init'd
template <int MODE>
__global__ __launch_bounds__(256)
void gemm_bt(const unsigned short* __restrict__ A,
             const unsigned short* __restrict__ B,
             void* __restrict__ Cv,
             const float* __restrict__ wscale_ptr,
             const float* __restrict__ bias,
             int N, int lda, int Kiter) {
  __shared__ unsigned short sA[128 * 32];
  __shared__ unsigned short sB[128 * 32];

  const int tid  = threadIdx.x;
  const int lane = tid & 63;
  const int wave = tid >> 6;
  const int wm   = wave & 1;   // 0..1
  const int wn   = wave >> 1;  // 0..1
  const int bm   = blockIdx.y * 128;
  const int bn   = blockIdx.x * 128;
  const int kbase = blockIdx.z * Kiter;

  // staging: thread t loads row (t>>2), swizzled 16B chunk ((t&3)^((t>>3)&3))
  const int csw = ((tid & 3) ^ ((tid >> 3) & 3)) * 8;
  const unsigned short* Ab = A + (size_t)(bm + (tid >> 2)) * lda + kbase + csw;
  const unsigned short* Bb = B + (size_t)(bn + (tid >> 2)) * lda + kbase + csw;

  f32x4 acc[4][4] = {};

  // fragment read: row (lane&15)+16i(+64wm), chunk (lane>>4), de-swizzled
  const int kc = ((lane >> 4) ^ ((lane >> 1) & 3)) * 8;
  const int la = (wm * 64 + (lane & 15)) * 32 + kc;
  const int lb = (wn * 64 + (lane & 15)) * 32 + kc;

  for (int k0 = 0; k0 < Kiter; k0 += 32) {
    gld16(Ab + k0,            sA + tid * 8);
    gld16(Ab + 64 * lda + k0, sA + 2048 + tid * 8);
    gld16(Bb + k0,            sB + tid * 8);
    gld16(Bb + 64 * lda + k0, sB + 2048 + tid * 8);
    __syncthreads();

    bf16x8 af[4], bfr[4];
#pragma unroll
    for (int i = 0; i < 4; ++i) af[i]  = *(const bf16x8*)(sA + la + i * 16 * 32);
#pragma unroll
    for (int j = 0; j < 4; ++j) bfr[j] = *(const bf16x8*)(sB + lb + j * 16 * 32);
#pragma unroll
    for (int i = 0; i < 4; ++i)
#pragma unroll
      for (int j = 0; j < 4; ++j)
        acc[i][j] = __builtin_amdgcn_mfma_f32_16x16x32_bf16(af[i], bfr[j], acc[i][j], 0, 0, 0);
    __syncthreads();
  }

  const float wscale = *wscale_ptr;
  float bv[4];
  if (MODE != 2) {
#pragma unroll
    for (int j = 0; j < 4; ++j) bv[j] = bias[bn + wn * 64 + j * 16 + (lane & 15)];
  }
#pragma unroll
  for (int i = 0; i < 4; ++i) {
    const int m0 = bm + wm * 64 + i * 16 + ((lane >> 4) << 2);
#pragma unroll
    for (int j = 0; j < 4; ++j) {
      const int n = bn + wn * 64 + j * 16 + (lane & 15);
#pragma unroll
      for (int r = 0; r < 4; ++r) {
        const size_t off = (size_t)(m0 + r) * N + n;
        if (MODE == 2) {
          unsafeAtomicAdd((float*)Cv + off, acc[i][j][r] * wscale);
        } else {
          float v = acc[i][j][r] * wscale + bv[j];
          if (MODE == 1) ((unsigned short*)Cv)[off] = f2bf(fast_gelu(v));
          else           ((float*)Cv)[off] = v;
        }
      }
    }
  }
}

extern "C" void kernel_launch(void* const* d_in, const int* in_sizes, int n_in,
                              void* d_out, int out_size, void* d_ws, size_t ws_size,
                              hipStream_t stream) {
  const float* x     = (const float*)d_in[0];
  const float* g1    = (const float*)d_in[1];
  const float* b1v   = (const float*)d_in[2];
  const float* w1    = (const float*)d_in[3];
  const float* bias1 = (const float*)d_in[4];
  const float* g2    = (const float*)d_in[5];
  const float* b2v   = (const float*)d_in[6];
  const float* w2    = (const float*)d_in[7];
  const float* bias2 = (const float*)d_in[8];
  float* out = (float*)d_out;

  char* ws = (char*)d_ws;
  float* scal          = (float*)ws;                 // [0]=mean|w1| [1]=mean|w2| (clipped)
  float* part          = (float*)(ws + 64);          // 2048 partial sums
  unsigned short* q1   = (unsigned short*)(ws + 16384);          // 4096x1024 bf16
  unsigned short* q2   = q1 + 4194304;                            // 1024x4096 bf16
  unsigned short* xn   = q2 + 4194304;                            // 8192x1024 bf16
  unsigned short* h    = xn + 8388608;                            // 8192x4096 bf16

  absum_kernel<<<2048, 256, 0, stream>>>(w1, w2, part);
  final_reduce<<<1, 256, 0, stream>>>(part, scal);
  quant_kernel<<<1024, 256, 0, stream>>>(w1, q1, w2, q2, scal);
  ln1_kernel<<<8192, 256, 0, stream>>>(x, g1, b1v, xn);
  init_out_kernel<<<8192, 256, 0, stream>>>(out, bias2);   // 2M float4
  gemm_bt<1><<<dim3(HID / 128, MROWS / 128), 256, 0, stream>>>(
      xn, q1, h, scal + 0, bias1, HID, DIM, DIM);
  ln2_kernel<<<8192, 256, 0, stream>>>(h, g2, b2v);
  gemm_bt<2><<<dim3(DIM / 128, MROWS / 128, 4), 256, 0, stream>>>(
      h, q2, out, scal + 1, nullptr, DIM, HID, HID / 4);
}

// Round 4
// 305.197 us; speedup vs baseline: 1.3717x; 1.3717x over previous
//
#include <hip/hip_runtime.h>
#include <cstdint>
#include <cstddef>

// Problem dims (fixed by reference): x [8,1024,1024] -> M=8192, dim=1024, hidden=4096
#define DIM   1024
#define HID   4096
#define MROWS 8192

typedef __attribute__((ext_vector_type(8))) __bf16 bf16x8;
typedef __attribute__((ext_vector_type(4))) float  f32x4;

__device__ __forceinline__ unsigned short f2bf(float f) {
  unsigned int u = __float_as_uint(f);
  u += 0x7fffu + ((u >> 16) & 1u);   // round-to-nearest-even
  return (unsigned short)(u >> 16);
}
__device__ __forceinline__ float bf2f(unsigned int lo16) {
  return __uint_as_float(lo16 << 16);
}

// tanh-form GELU: ~7 VALU instrs vs ~25 for erff; deviation from exact ~1e-3.
__device__ __forceinline__ float fast_gelu(float v) {
  float u = v * (0.79788456080286536f + 0.035677408136300125f * v * v);
  float e = __builtin_amdgcn_exp2f(u * 2.8853900817779268f);   // exp(2u)
  float r = __builtin_amdgcn_rcpf(e + 1.0f);
  return v - v * r;   // = v * e/(e+1) = 0.5 v (1+tanh(u))
}

// ---- async global->LDS, 16B per lane (m97 pattern) ----
__device__ __forceinline__ void gld16(const void* g, void* l) {
  auto* gp = reinterpret_cast<__attribute__((address_space(1))) unsigned int*>(
      reinterpret_cast<uintptr_t>(g));
  auto* lp = reinterpret_cast<__attribute__((address_space(3))) unsigned int*>(
      reinterpret_cast<uintptr_t>(l));
  __builtin_amdgcn_global_load_lds(gp, lp, 16, 0, 0);
}

// ---- block reduce (two values), 256 threads = 4 waves ----
__device__ __forceinline__ void block_reduce2(float& a, float& b, int tid) {
#pragma unroll
  for (int off = 32; off > 0; off >>= 1) {
    a += __shfl_xor(a, off, 64);
    b += __shfl_xor(b, off, 64);
  }
  __shared__ float red[8];
  if ((tid & 63) == 0) { red[tid >> 6] = a; red[4 + (tid >> 6)] = b; }
  __syncthreads();
  a = red[0] + red[1] + red[2] + red[3];
  b = red[4] + red[5] + red[6] + red[7];
}

// ---- stage 1: per-block partial sums of |w| (4096 floats per block) ----
// blocks 0..1023 -> w1, 1024..2047 -> w2 (both are 4M elements)
__global__ __launch_bounds__(256)
void absum_kernel(const float* __restrict__ w1, const float* __restrict__ w2,
                  float* __restrict__ part) {
  int tid = threadIdx.x;
  const float* w = (blockIdx.x < 1024) ? w1 : w2;
  int blk = blockIdx.x & 1023;
  const float4* base = (const float4*)w + (size_t)blk * 1024;
  float s = 0.f;
#pragma unroll
  for (int i = 0; i < 4; ++i) {
    float4 v = base[tid + i * 256];
    s += fabsf(v.x) + fabsf(v.y) + fabsf(v.z) + fabsf(v.w);
  }
#pragma unroll
  for (int off = 32; off > 0; off >>= 1) s += __shfl_xor(s, off, 64);
  __shared__ float red[4];
  if ((tid & 63) == 0) red[tid >> 6] = s;
  __syncthreads();
  if (tid == 0) part[blockIdx.x] = red[0] + red[1] + red[2] + red[3];
}

// ---- stage 2: final deterministic reduce -> clipped means for both weights ----
__global__ __launch_bounds__(256)
void final_reduce(const float* __restrict__ part, float* __restrict__ out) {
  int tid = threadIdx.x;
  float a = 0.f, b = 0.f;
  for (int i = tid; i < 1024; i += 256) { a += part[i]; b += part[1024 + i]; }
  block_reduce2(a, b, tid);
  if (tid == 0) {
    out[0] = fmaxf(a * (1.0f / 4194304.0f), 1e-5f);  // mean|w1| clipped
    out[1] = fmaxf(b * (1.0f / 4194304.0f), 1e-5f);  // mean|w2| clipped
  }
}

// ---- ternary quantize: q = clip(rint(w/mean),-1,1) stored as bf16 {-1,0,1} ----
// blocks 0..511 -> w1->q1 (scale[0]), 512..1023 -> w2->q2 (scale[1])
__global__ __launch_bounds__(256)
void quant_kernel(const float* __restrict__ w1, unsigned short* __restrict__ q1,
                  const float* __restrict__ w2, unsigned short* __restrict__ q2,
                  const float* __restrict__ meanp) {
  const int n4 = 1048576;
  const float* w;
  unsigned short* q;
  float sc;
  int bid = blockIdx.x;
  if (bid < 512) { w = w1; q = q1; sc = 1.0f / meanp[0]; }
  else           { w = w2; q = q2; sc = 1.0f / meanp[1]; bid -= 512; }
  int i = bid * 256 + threadIdx.x;
  for (; i < n4; i += 512 * 256) {
    float4 v = ((const float4*)w)[i];
    float t0 = fminf(fmaxf(rintf(v.x * sc), -1.f), 1.f);
    float t1 = fminf(fmaxf(rintf(v.y * sc), -1.f), 1.f);
    float t2 = fminf(fmaxf(rintf(v.z * sc), -1.f), 1.f);
    float t3 = fminf(fmaxf(rintf(v.w * sc), -1.f), 1.f);
    uint2 r;
    r.x = (unsigned)f2bf(t0) | ((unsigned)f2bf(t1) << 16);
    r.y = (unsigned)f2bf(t2) | ((unsigned)f2bf(t3) << 16);
    ((uint2*)q)[i] = r;
  }
}

// ---- LN1: fp32 [8192,1024] -> bf16 normalized ----
__global__ __launch_bounds__(256)
void ln1_kernel(const float* __restrict__ x, const float* __restrict__ g,
                const float* __restrict__ b, unsigned short* __restrict__ out) {
  int tid = threadIdx.x;
  const float4* xr = (const float4*)(x + (size_t)blockIdx.x * DIM);
  float4 v = xr[tid];
  float s  = v.x + v.y + v.z + v.w;
  float ss = v.x * v.x + v.y * v.y + v.z * v.z + v.w * v.w;
  block_reduce2(s, ss, tid);
  float mu  = s * (1.0f / DIM);
  float var = ss * (1.0f / DIM) - mu * mu;
  float rs  = rsqrtf(var + 1e-5f);
  float4 gg = ((const float4*)g)[tid];
  float4 bb = ((const float4*)b)[tid];
  uint2 r;
  r.x = (unsigned)f2bf((v.x - mu) * rs * gg.x + bb.x) |
        ((unsigned)f2bf((v.y - mu) * rs * gg.y + bb.y) << 16);
  r.y = (unsigned)f2bf((v.z - mu) * rs * gg.z + bb.z) |
        ((unsigned)f2bf((v.w - mu) * rs * gg.w + bb.w) << 16);
  *(uint2*)(out + (size_t)blockIdx.x * DIM + tid * 4) = r;
}

// ---- LN2: in-place on bf16 h [8192,4096] ----
__global__ __launch_bounds__(256)
void ln2_kernel(unsigned short* __restrict__ h, const float* __restrict__ g,
                const float* __restrict__ b) {
  int tid = threadIdx.x;
  unsigned short* hr = h + (size_t)blockIdx.x * HID;
  uint4 pa = ((uint4*)hr)[tid];
  uint4 pb = ((uint4*)hr)[tid + 256];
  float va[8], vb[8];
  {
    unsigned int* pu = (unsigned int*)&pa;
#pragma unroll
    for (int j = 0; j < 4; ++j) {
      va[2 * j]     = bf2f(pu[j] & 0xffffu);
      va[2 * j + 1] = __uint_as_float(pu[j] & 0xffff0000u);
    }
    pu = (unsigned int*)&pb;
#pragma unroll
    for (int j = 0; j < 4; ++j) {
      vb[2 * j]     = bf2f(pu[j] & 0xffffu);
      vb[2 * j + 1] = __uint_as_float(pu[j] & 0xffff0000u);
    }
  }
  float s = 0.f, ss = 0.f;
#pragma unroll
  for (int j = 0; j < 8; ++j) {
    s += va[j] + vb[j];
    ss += va[j] * va[j] + vb[j] * vb[j];
  }
  block_reduce2(s, ss, tid);
  float mu  = s * (1.0f / HID);
  float var = ss * (1.0f / HID) - mu * mu;
  float rs  = rsqrtf(var + 1e-5f);

  const float4* g4 = (const float4*)g;
  const float4* b4 = (const float4*)b;
  float4 ga0 = g4[tid * 2], ga1 = g4[tid * 2 + 1];
  float4 ba0 = b4[tid * 2], bb1 = b4[tid * 2 + 1];
  float4 gb0 = g4[(tid + 256) * 2], gb1 = g4[(tid + 256) * 2 + 1];
  float4 bb0 = b4[(tid + 256) * 2], bb3 = b4[(tid + 256) * 2 + 1];
  float gva[8] = {ga0.x, ga0.y, ga0.z, ga0.w, ga1.x, ga1.y, ga1.z, ga1.w};
  float bva[8] = {ba0.x, ba0.y, ba0.z, ba0.w, bb1.x, bb1.y, bb1.z, bb1.w};
  float gvb[8] = {gb0.x, gb0.y, gb0.z, gb0.w, gb1.x, gb1.y, gb1.z, gb1.w};
  float bvb[8] = {bb0.x, bb0.y, bb0.z, bb0.w, bb3.x, bb3.y, bb3.z, bb3.w};

  uint4 ra, rb;
  unsigned int* ru = (unsigned int*)&ra;
#pragma unroll
  for (int j = 0; j < 4; ++j) {
    unsigned lo = f2bf((va[2 * j] - mu) * rs * gva[2 * j] + bva[2 * j]);
    unsigned hi = f2bf((va[2 * j + 1] - mu) * rs * gva[2 * j + 1] + bva[2 * j + 1]);
    ru[j] = lo | (hi << 16);
  }
  ru = (unsigned int*)&rb;
#pragma unroll
  for (int j = 0; j < 4; ++j) {
    unsigned lo = f2bf((vb[2 * j] - mu) * rs * gvb[2 * j] + bvb[2 * j]);
    unsigned hi = f2bf((vb[2 * j + 1] - mu) * rs * gvb[2 * j + 1] + bvb[2 * j + 1]);
    ru[j] = lo | (hi << 16);
  }
  ((uint4*)hr)[tid]       = ra;
  ((uint4*)hr)[tid + 256] = rb;
}

// ---- GEMM C[m,n] = sum_k A[m,k]*B[n,k] * wscale + bias[n] (+gelu) ----
// A: bf16 [M,K] row-major; B: bf16 ternary [N,K] row-major.
// 128x128 tile, BK=64, 256 thr = 4 waves (2x2 of 64x64), 16x16x32 bf16 MFMA.
// BK=64 halves the number of __syncthreads()+vmcnt(0) barrier drains vs BK=32;
// LDS = 2x16KB -> 5 blocks/CU LDS-limit (above the ~3 VGPR limit, no occ loss).
//
// LDS XOR-granule swizzle (conflict-free): 16B chunk c of row r stored at
// position c ^ (r&7). global_load_lds forces dest = waveBase+16*lane, so the
// swizzle is applied to the global SOURCE chunk each lane fetches and undone
// with a lane-constant XOR at fragment-read time.
//
// XCD swizzle: remap flat block id so each XCD (presumed id%8 dispatch) owns
// 8 contiguous 128-row A-bands with ALL their column tiles -> the 1MB A-band
// stays in that XCD's 4MB L2 across its column blocks (cuts GEMM2's measured
// 286MB HBM fetch). Wrong mapping assumption => perf-neutral, never wrong.
//
// MODE 0: store fp32 (v*wscale + bias)      MODE 1: store bf16 gelu(...)
template <int MODE>
__global__ __launch_bounds__(256)
void gemm_bt(const unsigned short* __restrict__ A,
             const unsigned short* __restrict__ B,
             void* __restrict__ Cv,
             const float* __restrict__ wscale_ptr,
             const float* __restrict__ bias,
             int N, int K) {
  __shared__ unsigned short sA[128 * 64];
  __shared__ unsigned short sB[128 * 64];

  const int tid  = threadIdx.x;
  const int lane = tid & 63;
  const int wave = tid >> 6;
  const int wm   = wave & 1;   // 0..1
  const int wn   = wave >> 1;  // 0..1

  // XCD-aware remap of (bm, bn)
  const int nbx  = gridDim.x;                    // column tiles
  const int id   = blockIdx.y * nbx + blockIdx.x;
  const int xcd  = id & 7;
  const int slot = id >> 3;
  const int bandsPerXcd = gridDim.y >> 3;        // 8 for both GEMMs
  const int band = xcd * bandsPerXcd + slot / nbx;
  const int col  = slot - (slot / nbx) * nbx;
  const int bm   = band * 128;
  const int bn   = col * 128;

  // staging: thread t, round i (i=0..3): row 32i+(t>>3), stored chunk t&7,
  // global chunk (t&7)^((t>>3)&7)  [(32i) % 8 == 0 so r&7 == (t>>3)&7]
  const int csw = (((tid & 7) ^ ((tid >> 3) & 7))) * 8;
  const unsigned short* Ab = A + (size_t)(bm + (tid >> 3)) * K + csw;
  const unsigned short* Bb = B + (size_t)(bn + (tid >> 3)) * K + csw;

  f32x4 acc[4][4] = {};

  // fragment read: row m = w*64 + i*16 + (lane&15); k-granule (half h) =
  // h*4 + (lane>>4); stored position = granule ^ (m&7) = granule ^ (lane&7)
  const int rowA = (wm * 64 + (lane & 15)) * 64;
  const int rowB = (wn * 64 + (lane & 15)) * 64;
  const int p0 = ((0 + (lane >> 4)) ^ (lane & 7)) * 8;   // k-half 0
  const int p1 = ((4 + (lane >> 4)) ^ (lane & 7)) * 8;   // k-half 1

  for (int k0 = 0; k0 < K; k0 += 64) {
#pragma unroll
    for (int i = 0; i < 4; ++i) {
      gld16(Ab + (size_t)(32 * i) * K + k0, sA + i * 2048 + tid * 8);
      gld16(Bb + (size_t)(32 * i) * K + k0, sB + i * 2048 + tid * 8);
    }
    __syncthreads();

#pragma unroll
    for (int h = 0; h < 2; ++h) {
      const int ph = h ? p1 : p0;
      bf16x8 af[4], bfr[4];
#pragma unroll
      for (int i = 0; i < 4; ++i) af[i]  = *(const bf16x8*)(sA + rowA + i * 1024 + ph);
#pragma unroll
      for (int j = 0; j < 4; ++j) bfr[j] = *(const bf16x8*)(sB + rowB + j * 1024 + ph);
#pragma unroll
      for (int i = 0; i < 4; ++i)
#pragma unroll
        for (int j = 0; j < 4; ++j)
          acc[i][j] = __builtin_amdgcn_mfma_f32_16x16x32_bf16(af[i], bfr[j], acc[i][j], 0, 0, 0);
    }
    __syncthreads();
  }

  const float wscale = *wscale_ptr;
  float bv[4];
#pragma unroll
  for (int j = 0; j < 4; ++j) bv[j] = bias[bn + wn * 64 + j * 16 + (lane & 15)];
#pragma unroll
  for (int i = 0; i < 4; ++i) {
    const int m0 = bm + wm * 64 + i * 16 + ((lane >> 4) << 2);
#pragma unroll
    for (int j = 0; j < 4; ++j) {
      const int n = bn + wn * 64 + j * 16 + (lane & 15);
#pragma unroll
      for (int r = 0; r < 4; ++r) {
        float v = acc[i][j][r] * wscale + bv[j];
        const size_t off = (size_t)(m0 + r) * N + n;
        if (MODE == 1) ((unsigned short*)Cv)[off] = f2bf(fast_gelu(v));
        else           ((float*)Cv)[off] = v;
      }
    }
  }
}

extern "C" void kernel_launch(void* const* d_in, const int* in_sizes, int n_in,
                              void* d_out, int out_size, void* d_ws, size_t ws_size,
                              hipStream_t stream) {
  const float* x     = (const float*)d_in[0];
  const float* g1    = (const float*)d_in[1];
  const float* b1v   = (const float*)d_in[2];
  const float* w1    = (const float*)d_in[3];
  const float* bias1 = (const float*)d_in[4];
  const float* g2    = (const float*)d_in[5];
  const float* b2v   = (const float*)d_in[6];
  const float* w2    = (const float*)d_in[7];
  const float* bias2 = (const float*)d_in[8];
  float* out = (float*)d_out;

  char* ws = (char*)d_ws;
  float* scal          = (float*)ws;                 // [0]=mean|w1| [1]=mean|w2| (clipped)
  float* part          = (float*)(ws + 64);          // 2048 partial sums
  unsigned short* q1   = (unsigned short*)(ws + 16384);          // 4096x1024 bf16
  unsigned short* q2   = q1 + 4194304;                            // 1024x4096 bf16
  unsigned short* xn   = q2 + 4194304;                            // 8192x1024 bf16
  unsigned short* h    = xn + 8388608;                            // 8192x4096 bf16

  absum_kernel<<<2048, 256, 0, stream>>>(w1, w2, part);
  final_reduce<<<1, 256, 0, stream>>>(part, scal);
  quant_kernel<<<1024, 256, 0, stream>>>(w1, q1, w2, q2, scal);
  ln1_kernel<<<8192, 256, 0, stream>>>(x, g1, b1v, xn);
  gemm_bt<1><<<dim3(HID / 128, MROWS / 128), 256, 0, stream>>>(
      xn, q1, h, scal + 0, bias1, HID, DIM);
  ln2_kernel<<<8192, 256, 0, stream>>>(h, g2, b2v);
  gemm_bt<0><<<dim3(DIM / 128, MROWS / 128), 256, 0, stream>>>(
      h, q2, out, scal + 1, bias2, DIM, HID);
}